// Round 2
// baseline (1283.242 us; speedup 1.0000x reference)
//
#include <hip/hip_runtime.h>

#define D 256
typedef unsigned short u16;
using short8  = __attribute__((ext_vector_type(8))) short;
using ushort8 = __attribute__((ext_vector_type(8))) unsigned short;
using f32x4   = __attribute__((ext_vector_type(4))) float;

#define BCHUNK  4096     // edges per binning block
#define FBINCAP 17500    // per fine-bin capacity (avg 16384, ~8.7 sigma margin)

__device__ __forceinline__ u16 f2bf(float f) {
    unsigned u = __float_as_uint(f);
    unsigned r = (u + 0x7FFFu + ((u >> 16) & 1u)) >> 16;
    return (u16)r;
}
__device__ __forceinline__ float bf2f(u16 v) {
    return __uint_as_float(((unsigned)v) << 16);
}

__device__ __forceinline__ void load_lds16(const u16* g, u16* l) {
    __builtin_amdgcn_global_load_lds(
        (const __attribute__((address_space(1))) void*)g,
        (__attribute__((address_space(3))) void*)l, 16, 0, 0);
}

// ---------------- CSR build ----------------

__global__ void k_initcur(int* __restrict__ bincur, int nfbin) {
    int i = threadIdx.x;
    if (i < nfbin) bincur[i] = i * FBINCAP;
}

// Fine-bin edges (512-node dst ranges). Per block: LDS hist over its 4096-edge
// chunk, one reserve atomic per touched bin (<=196/block), ranked contiguous
// writes into per-bin regions. pack = src(17b) | dst_local(9b)<<17.
__global__ __launch_bounds__(256)
void k_binf(const int* __restrict__ src, const int* __restrict__ dst,
            int* __restrict__ bincur, unsigned* __restrict__ bins,
            int E, int nfbin) {
    __shared__ int cnt[256];
    __shared__ int bpos[256];
    int t = threadIdx.x;
    int base = blockIdx.x * BCHUNK;
    cnt[t] = 0;
    __syncthreads();
    int lim = E - base; if (lim > BCHUNK) lim = BCHUNK;
    for (int i = t; i < lim; i += 256)
        atomicAdd(&cnt[dst[base + i] >> 9], 1);
    __syncthreads();
    if (t < nfbin) {
        int c = cnt[t];
        bpos[t] = c > 0 ? atomicAdd(&bincur[t], c) : 0;
    }
    __syncthreads();
    cnt[t] = 0;
    __syncthreads();
    for (int i = t; i < lim; i += 256) {
        int d = dst[base + i], s = src[base + i];
        int fb = d >> 9;
        int r = atomicAdd(&cnt[fb], 1);
        bins[(size_t)bpos[fb] + r] = (unsigned)s | ((unsigned)(d & 511) << 17);
    }
}

// One block per fine bin: LDS hist(512) -> LDS scan -> LDS placement ->
// coalesced streaming write of srcs + direct offs/ends (padded CSR).
__global__ __launch_bounds__(256)
void k_csrf(const unsigned* __restrict__ bins, const int* __restrict__ bincur,
            int* __restrict__ offs, int* __restrict__ ends,
            int* __restrict__ srcs, int N) {
    __shared__ int cnt[512];
    __shared__ int cur[512];
    __shared__ int ssum[256];
    __shared__ int loc[FBINCAP];
    int b = blockIdx.x, t = threadIdx.x;
    int bbase = b * FBINCAP;
    int ecnt = bincur[b] - bbase;
    cnt[t] = 0; cnt[t + 256] = 0;
    __syncthreads();
    const unsigned* bp = bins + bbase;
    for (int i = t; i < ecnt; i += 256)
        atomicAdd(&cnt[bp[i] >> 17], 1);
    __syncthreads();
    int a0 = cnt[2 * t], a1 = cnt[2 * t + 1];
    ssum[t] = a0 + a1;
    __syncthreads();
    for (int o = 1; o < 256; o <<= 1) {
        int x = (t >= o) ? ssum[t - o] : 0;
        __syncthreads();
        ssum[t] += x;
        __syncthreads();
    }
    int excl = ssum[t] - (a0 + a1);
    cur[2 * t] = excl;
    cur[2 * t + 1] = excl + a0;
    int nbase = b << 9;
    int l0 = nbase + 2 * t, l1 = l0 + 1;
    if (l0 < N) { offs[l0] = bbase + excl;      ends[l0] = bbase + excl + a0; }
    if (l1 < N) { offs[l1] = bbase + excl + a0; ends[l1] = bbase + excl + a0 + a1; }
    __syncthreads();
    for (int i = t; i < ecnt; i += 256) {
        unsigned v = bp[i];
        int p = atomicAdd(&cur[v >> 17], 1);
        loc[p] = (int)(v & 0x1FFFFu);
    }
    __syncthreads();
    for (int i = t; i < ecnt; i += 256)
        srcs[bbase + i] = loc[i];
}

// ---------------- embedding gather -> bf16 ----------------

__global__ void k_gather_bf(const int* __restrict__ x, const float* __restrict__ emb,
                            u16* __restrict__ h, int N) {
    int idx = blockIdx.x * blockDim.x + threadIdx.x;
    if (idx >= N * 64) return;
    int node = idx >> 6, c = idx & 63;
    int s = x[node];
    float4 v = ((const float4*)emb)[(size_t)s * 64 + c];
    ushort4 o;
    o.x = f2bf(v.x); o.y = f2bf(v.y); o.z = f2bf(v.z); o.w = f2bf(v.w);
    ((ushort4*)h)[(size_t)node * 64 + c] = o;
}

// ---------------- weight fp32 -> bf16 ----------------

__global__ void k_cvtw(const float* w0, const float* w1, const float* w2,
                       const float* w3, const float* w4, const float* w5,
                       const float* w6, u16* __restrict__ out) {
    int idx = blockIdx.x * blockDim.x + threadIdx.x;
    if (idx >= 7 * 65536) return;
    int m = idx >> 16, off = idx & 65535;
    const float* w = w0;
    if (m == 1) w = w1; else if (m == 2) w = w2; else if (m == 3) w = w3;
    else if (m == 4) w = w4; else if (m == 5) w = w5; else if (m == 6) w = w6;
    out[idx] = f2bf(w[off]);
}

// ---------------- fused full-row mean aggregation ----------------
// One wave per dst node, full 512B row. 2 edge slots (q=lane>>5) x 32 chunk
// lanes; 4-deep unroll => 8 edges / 4 KB in flight per wave. srcs read once
// per layer (was twice with the half-split kernels).

__global__ __launch_bounds__(256)
void k_agg(const u16* __restrict__ h, const int* __restrict__ offs,
           const int* __restrict__ ends, const int* __restrict__ srcs,
           u16* __restrict__ out, int N) {
    int wid = (blockIdx.x * blockDim.x + threadIdx.x) >> 6;
    int lane = threadIdx.x & 63;
    if (wid >= N) return;
    int beg = offs[wid], end = ends[wid];
    int q = lane >> 5;             // edge slot 0..1
    int cl = lane & 31;            // 16B chunk within the 512B row
    const u16* hb = h + cl * 8;
    float acc[8];
    #pragma unroll
    for (int i = 0; i < 8; i++) acc[i] = 0.f;
    int e = beg + q;
    for (; e + 6 < end; e += 8) {
        int j0 = srcs[e], j1 = srcs[e + 2], j2 = srcs[e + 4], j3 = srcs[e + 6];
        ushort8 v0 = *(const ushort8*)&hb[(size_t)j0 * D];
        ushort8 v1 = *(const ushort8*)&hb[(size_t)j1 * D];
        ushort8 v2 = *(const ushort8*)&hb[(size_t)j2 * D];
        ushort8 v3 = *(const ushort8*)&hb[(size_t)j3 * D];
        #pragma unroll
        for (int i = 0; i < 8; i++)
            acc[i] += (bf2f(v0[i]) + bf2f(v1[i])) + (bf2f(v2[i]) + bf2f(v3[i]));
    }
    for (; e < end; e += 2) {
        int j = srcs[e];
        ushort8 v = *(const ushort8*)&hb[(size_t)j * D];
        #pragma unroll
        for (int i = 0; i < 8; i++) acc[i] += bf2f(v[i]);
    }
    #pragma unroll
    for (int i = 0; i < 8; i++) acc[i] += __shfl_xor(acc[i], 32);
    if (q == 0) {
        int dg = end - beg;
        float inv = 1.0f / (float)(dg < 1 ? 1 : dg);
        ushort8 o;
        #pragma unroll
        for (int i = 0; i < 8; i++) o[i] = f2bf(acc[i] * inv);
        *(ushort8*)&out[(size_t)wid * D + cl * 8] = o;
    }
}

// ---------------- fused MFMA GEMM (dbuf + prefetch + XOR swizzle) ----------------
// out[M,256] = epi( sum_p Ap[M,256] @ Wp[256,256]^T + bias ), bf16 in, fp32 acc.
// BM=128, BN=256, BK=64; 512 thr = 8 waves (2Mx4N), per-wave 64x64 = 4x4 frags.
// LDS 96 KB (dbuf A 2x16K + B 2x32K) -> 1 block/CU. Pipeline (T3-minimum):
// issue next tile's global_load_lds BEFORE compute of current tile, one
// barrier per K-step; the DMA flies under ds_read+MFMA. LDS rows are 128 B:
// XOR swizzle byte^=(row&7)<<4 applied on the per-lane GLOBAL source
// (load_lds dest must stay linear, rule 21) and again on the ds_read
// address -> 2-way (free) bank aliasing instead of the old 8-way conflict.
// __syncthreads() per K-step == vmcnt(0)+lgkmcnt(0)+barrier (we drain
// vmcnt to 0 each step anyway; safer than raw s_barrier + asm waitcnt).
// K accumulation order identical to the original BK=32 kernel.

__global__ __launch_bounds__(512, 2)
void k_fgemm(const u16* __restrict__ A0, const u16* __restrict__ W0,
             const u16* __restrict__ A1, const u16* __restrict__ W1,
             int npairs,
             const float* __restrict__ bias, const float* __restrict__ prelu_a,
             void* __restrict__ outp, int out_bf16, int M) {
    __shared__ u16 As[2][128 * 64];   // [buf][row*64 + elem]
    __shared__ u16 Bs[2][256 * 64];
    int t = threadIdx.x;
    int wave = t >> 6, lane = t & 63;
    int r = lane & 15, quad = lane >> 4;
    int wm = (wave & 1) * 64;
    int wn = (wave >> 1) * 64;
    int m0 = blockIdx.x * 128;

    f32x4 acc[4][4];
    #pragma unroll
    for (int i = 0; i < 4; i++)
        #pragma unroll
        for (int j = 0; j < 4; j++)
            acc[i][j] = (f32x4){0.f, 0.f, 0.f, 0.f};

    // staging geometry: per wave-load, 64 lanes x 16B = 8 rows x 128B.
    int l8   = lane >> 3;                 // row within 8-row group == row&7
    int cb   = (lane & 7) * 16;           // dest byte col in [0,128)
    int scol = (cb ^ (l8 << 4)) >> 1;     // pre-swizzled source col (u16 elems)
    int arow = wave * 8 + l8;             // + l*64 per load

    int nkt = npairs * 4;                 // K-steps of 64 (K=256 per pair)

    auto STAGE = [&](int buf, int kt) {
        const u16* Ag = (kt >= 4) ? A1 : A0;
        const u16* Wg = (kt >= 4) ? W1 : W0;
        int k0 = (kt & 3) * 64;
        #pragma unroll
        for (int l = 0; l < 2; l++) {
            int row = l * 64 + arow;
            load_lds16(Ag + (size_t)(m0 + row) * D + k0 + scol,
                       &As[buf][l * 4096 + wave * 512]);
        }
        #pragma unroll
        for (int l = 0; l < 4; l++) {
            int row = l * 64 + arow;
            load_lds16(Wg + (size_t)row * D + k0 + scol,
                       &Bs[buf][l * 4096 + wave * 512]);
        }
    };

    STAGE(0, 0);
    __syncthreads();

    int cur = 0;
    for (int kt = 0; kt < nkt; ++kt) {
        if (kt + 1 < nkt) STAGE(cur ^ 1, kt + 1);

        short8 a[2][4], b[2][4];
        #pragma unroll
        for (int ks = 0; ks < 2; ks++) {
            #pragma unroll
            for (int mt = 0; mt < 4; mt++) {
                int row = wm + mt * 16 + r;
                int col = (ks * 64 + quad * 16) ^ ((r & 7) << 4);
                a[ks][mt] = *(const short8*)&As[cur][row * 64 + (col >> 1)];
            }
            #pragma unroll
            for (int nt = 0; nt < 4; nt++) {
                int row = wn + nt * 16 + r;
                int col = (ks * 64 + quad * 16) ^ ((r & 7) << 4);
                b[ks][nt] = *(const short8*)&Bs[cur][row * 64 + (col >> 1)];
            }
        }

        __builtin_amdgcn_s_setprio(1);
        #pragma unroll
        for (int ks = 0; ks < 2; ks++)
            #pragma unroll
            for (int mt = 0; mt < 4; mt++)
                #pragma unroll
                for (int nt = 0; nt < 4; nt++)
                    acc[mt][nt] = __builtin_amdgcn_mfma_f32_16x16x32_bf16(
                        a[ks][mt], b[ks][nt], acc[mt][nt], 0, 0, 0);
        __builtin_amdgcn_s_setprio(0);

        __syncthreads();
        cur ^= 1;
    }

    float pa = prelu_a ? *prelu_a : 0.f;
    int dop = prelu_a != nullptr;
    #pragma unroll
    for (int nt = 0; nt < 4; nt++) {
        int col = wn + nt * 16 + r;
        float bv = bias ? bias[col] : 0.f;
        #pragma unroll
        for (int mt = 0; mt < 4; mt++) {
            #pragma unroll
            for (int i = 0; i < 4; i++) {
                int row = m0 + wm + mt * 16 + quad * 4 + i;
                if (row < M) {
                    float v = acc[mt][nt][i] + bv;
                    if (dop) v = (v >= 0.f) ? v : pa * v;
                    if (out_bf16)
                        ((u16*)outp)[(size_t)row * D + col] = f2bf(v);
                    else
                        ((float*)outp)[(size_t)row * D + col] = v;
                }
            }
        }
    }
}

// ---------------- launcher ----------------

extern "C" void kernel_launch(void* const* d_in, const int* in_sizes, int n_in,
                              void* d_out, int out_size, void* d_ws, size_t ws_size,
                              hipStream_t stream) {
    const int*   x    = (const int*)d_in[0];
    const int*   ei   = (const int*)d_in[1];
    const float* emb  = (const float*)d_in[3];
    const float* Wl[3] = {(const float*)d_in[4],  (const float*)d_in[8],  (const float*)d_in[12]};
    const float* bl[3] = {(const float*)d_in[5],  (const float*)d_in[9],  (const float*)d_in[13]};
    const float* Wr[3] = {(const float*)d_in[6],  (const float*)d_in[10], (const float*)d_in[14]};
    const float* pa[3] = {(const float*)d_in[7],  (const float*)d_in[11], (const float*)d_in[15]};
    const float* Wout = (const float*)d_in[16];
    const float* bout = (const float*)d_in[17];

    int N = in_sizes[0];
    int E = in_sizes[1] / 2;
    const int* src = ei;
    const int* dst = ei + E;
    int nfbin = (N + 511) >> 9;    // 196 for N=100000

    char* ws = (char*)d_ws;
    size_t off = 0;
    auto walloc = [&](size_t bytes) -> void* {
        void* p = ws + off;
        off += (bytes + 255) & ~(size_t)255;
        return p;
    };
    // tile staging over-reads up to ~49 KB past row M-1: keep activations mid-ws
    u16* hA   = (u16*)walloc((size_t)N * D * sizeof(u16));
    u16* hB   = (u16*)walloc((size_t)N * D * sizeof(u16));
    u16* mean = (u16*)walloc((size_t)N * D * sizeof(u16));
    u16* wbf  = (u16*)walloc((size_t)7 * 65536 * sizeof(u16));
    int* offs   = (int*)walloc((size_t)N * sizeof(int));
    int* ends   = (int*)walloc((size_t)N * sizeof(int));
    int* bincur = (int*)walloc(1024);
    unsigned* bins = (unsigned*)walloc((size_t)nfbin * FBINCAP * sizeof(unsigned));
    int* srcs   = (int*)walloc((size_t)nfbin * FBINCAP * sizeof(int));

    u16* Wlb[3] = {wbf + 0 * 65536, wbf + 2 * 65536, wbf + 4 * 65536};
    u16* Wrb[3] = {wbf + 1 * 65536, wbf + 3 * 65536, wbf + 5 * 65536};
    u16* Woutb  = wbf + 6 * 65536;

    // --- weights -> bf16 ---
    k_cvtw<<<(7 * 65536 + 255) / 256, 256, 0, stream>>>(
        Wl[0], Wr[0], Wl[1], Wr[1], Wl[2], Wr[2], Wout, wbf);

    // --- CSR build: fine-bin + in-LDS sort ---
    k_initcur<<<1, 256, 0, stream>>>(bincur, nfbin);
    int bb = (E + BCHUNK - 1) / BCHUNK;
    k_binf<<<bb, 256, 0, stream>>>(src, dst, bincur, bins, E, nfbin);
    k_csrf<<<nfbin, 256, 0, stream>>>(bins, bincur, offs, ends, srcs, N);

    // --- h0 = bf16(emb[x]) ---
    k_gather_bf<<<(N * 64 + 255) / 256, 256, 0, stream>>>(x, emb, hA, N);

    int mb   = (N + 127) / 128;
    int aggb = (N * 64 + 255) / 256;   // one wave per dst node

    // layer 1: hA -> hB
    k_agg<<<aggb, 256, 0, stream>>>(hA, offs, ends, srcs, mean, N);
    k_fgemm<<<mb, 512, 0, stream>>>(mean, Wlb[0], hA, Wrb[0], 2, bl[0], pa[0], hB, 1, N);
    // layer 2: hB -> hA
    k_agg<<<aggb, 256, 0, stream>>>(hB, offs, ends, srcs, mean, N);
    k_fgemm<<<mb, 512, 0, stream>>>(mean, Wlb[1], hB, Wrb[1], 2, bl[1], pa[1], hA, 1, N);
    // layer 3: hA -> hB
    k_agg<<<aggb, 256, 0, stream>>>(hA, offs, ends, srcs, mean, N);
    k_fgemm<<<mb, 512, 0, stream>>>(mean, Wlb[2], hA, Wrb[2], 2, bl[2], pa[2], hB, 1, N);
    // output projection -> fp32 d_out
    k_fgemm<<<mb, 512, 0, stream>>>(hB, Woutb, hB, Woutb, 1, bout, nullptr, d_out, 0, N);
}

// Round 3
// 1179.476 us; speedup vs baseline: 1.0880x; 1.0880x over previous
//
#include <hip/hip_runtime.h>

#define D 256
typedef unsigned short u16;
using short8  = __attribute__((ext_vector_type(8))) short;
using ushort8 = __attribute__((ext_vector_type(8))) unsigned short;
using f32x4   = __attribute__((ext_vector_type(4))) float;

#define BCHUNK  4096     // edges per binning block
#define FBINCAP 17500    // per fine-bin capacity (avg 16384, ~8.7 sigma margin)

__device__ __forceinline__ u16 f2bf(float f) {
    unsigned u = __float_as_uint(f);
    unsigned r = (u + 0x7FFFu + ((u >> 16) & 1u)) >> 16;
    return (u16)r;
}
__device__ __forceinline__ float bf2f(u16 v) {
    return __uint_as_float(((unsigned)v) << 16);
}

__device__ __forceinline__ void load_lds16(const u16* g, u16* l) {
    __builtin_amdgcn_global_load_lds(
        (const __attribute__((address_space(1))) void*)g,
        (__attribute__((address_space(3))) void*)l, 16, 0, 0);
}

// ---------------- CSR build ----------------

__global__ void k_initcur(int* __restrict__ bincur, int nfbin) {
    int i = threadIdx.x;
    if (i < nfbin) bincur[i] = i * FBINCAP;
}

__global__ __launch_bounds__(256)
void k_binf(const int* __restrict__ src, const int* __restrict__ dst,
            int* __restrict__ bincur, unsigned* __restrict__ bins,
            int E, int nfbin) {
    __shared__ int cnt[256];
    __shared__ int bpos[256];
    int t = threadIdx.x;
    int base = blockIdx.x * BCHUNK;
    cnt[t] = 0;
    __syncthreads();
    int lim = E - base; if (lim > BCHUNK) lim = BCHUNK;
    for (int i = t; i < lim; i += 256)
        atomicAdd(&cnt[dst[base + i] >> 9], 1);
    __syncthreads();
    if (t < nfbin) {
        int c = cnt[t];
        bpos[t] = c > 0 ? atomicAdd(&bincur[t], c) : 0;
    }
    __syncthreads();
    cnt[t] = 0;
    __syncthreads();
    for (int i = t; i < lim; i += 256) {
        int d = dst[base + i], s = src[base + i];
        int fb = d >> 9;
        int r = atomicAdd(&cnt[fb], 1);
        bins[(size_t)bpos[fb] + r] = (unsigned)s | ((unsigned)(d & 511) << 17);
    }
}

__global__ __launch_bounds__(256)
void k_csrf(const unsigned* __restrict__ bins, const int* __restrict__ bincur,
            int* __restrict__ offs, int* __restrict__ ends,
            int* __restrict__ srcs, int N) {
    __shared__ int cnt[512];
    __shared__ int cur[512];
    __shared__ int ssum[256];
    __shared__ int loc[FBINCAP];
    int b = blockIdx.x, t = threadIdx.x;
    int bbase = b * FBINCAP;
    int ecnt = bincur[b] - bbase;
    cnt[t] = 0; cnt[t + 256] = 0;
    __syncthreads();
    const unsigned* bp = bins + bbase;
    for (int i = t; i < ecnt; i += 256)
        atomicAdd(&cnt[bp[i] >> 17], 1);
    __syncthreads();
    int a0 = cnt[2 * t], a1 = cnt[2 * t + 1];
    ssum[t] = a0 + a1;
    __syncthreads();
    for (int o = 1; o < 256; o <<= 1) {
        int x = (t >= o) ? ssum[t - o] : 0;
        __syncthreads();
        ssum[t] += x;
        __syncthreads();
    }
    int excl = ssum[t] - (a0 + a1);
    cur[2 * t] = excl;
    cur[2 * t + 1] = excl + a0;
    int nbase = b << 9;
    int l0 = nbase + 2 * t, l1 = l0 + 1;
    if (l0 < N) { offs[l0] = bbase + excl;      ends[l0] = bbase + excl + a0; }
    if (l1 < N) { offs[l1] = bbase + excl + a0; ends[l1] = bbase + excl + a0 + a1; }
    __syncthreads();
    for (int i = t; i < ecnt; i += 256) {
        unsigned v = bp[i];
        int p = atomicAdd(&cur[v >> 17], 1);
        loc[p] = (int)(v & 0x1FFFFu);
    }
    __syncthreads();
    for (int i = t; i < ecnt; i += 256)
        srcs[bbase + i] = loc[i];
}

// ---------------- embedding gather -> bf16 ----------------

__global__ void k_gather_bf(const int* __restrict__ x, const float* __restrict__ emb,
                            u16* __restrict__ h, int N) {
    int idx = blockIdx.x * blockDim.x + threadIdx.x;
    if (idx >= N * 64) return;
    int node = idx >> 6, c = idx & 63;
    int s = x[node];
    float4 v = ((const float4*)emb)[(size_t)s * 64 + c];
    ushort4 o;
    o.x = f2bf(v.x); o.y = f2bf(v.y); o.z = f2bf(v.z); o.w = f2bf(v.w);
    ((ushort4*)h)[(size_t)node * 64 + c] = o;
}

// ---------------- weight fp32 -> bf16 ----------------

__global__ void k_cvtw(const float* w0, const float* w1, const float* w2,
                       const float* w3, const float* w4, const float* w5,
                       const float* w6, u16* __restrict__ out) {
    int idx = blockIdx.x * blockDim.x + threadIdx.x;
    if (idx >= 7 * 65536) return;
    int m = idx >> 16, off = idx & 65535;
    const float* w = w0;
    if (m == 1) w = w1; else if (m == 2) w = w2; else if (m == 3) w = w3;
    else if (m == 4) w = w4; else if (m == 5) w = w5; else if (m == 6) w = w6;
    out[idx] = f2bf(w[off]);
}

// ---------------- mean aggregation, 128-col half (proven R0 kernel) ----------------
// Per edge: 256B (two 128B lines). Working set 25.6MB/pass.

__global__ __launch_bounds__(256)
void k_agg_h(const u16* __restrict__ h, const int* __restrict__ offs,
             const int* __restrict__ ends, const int* __restrict__ srcs,
             u16* __restrict__ out, int colOff, int N) {
    int wid = (blockIdx.x * blockDim.x + threadIdx.x) >> 6;
    int lane = threadIdx.x & 63;
    if (wid >= N) return;
    int beg = offs[wid], end = ends[wid];
    int q = lane >> 4;             // edge slot 0..3
    int cl = lane & 15;            // 16B chunk within the 256B half-row
    const u16* hb = h + colOff + cl * 8;
    float acc[8];
    #pragma unroll
    for (int i = 0; i < 8; i++) acc[i] = 0.f;
    int e = beg + q;
    for (; e + 12 < end; e += 16) {
        int j0 = srcs[e], j1 = srcs[e + 4], j2 = srcs[e + 8], j3 = srcs[e + 12];
        ushort8 v0 = *(const ushort8*)&hb[(size_t)j0 * D];
        ushort8 v1 = *(const ushort8*)&hb[(size_t)j1 * D];
        ushort8 v2 = *(const ushort8*)&hb[(size_t)j2 * D];
        ushort8 v3 = *(const ushort8*)&hb[(size_t)j3 * D];
        #pragma unroll
        for (int i = 0; i < 8; i++)
            acc[i] += (bf2f(v0[i]) + bf2f(v1[i])) + (bf2f(v2[i]) + bf2f(v3[i]));
    }
    for (; e < end; e += 4) {
        int j = srcs[e];
        ushort8 v = *(const ushort8*)&hb[(size_t)j * D];
        #pragma unroll
        for (int i = 0; i < 8; i++) acc[i] += bf2f(v[i]);
    }
    #pragma unroll
    for (int i = 0; i < 8; i++) {
        acc[i] += __shfl_xor(acc[i], 16);
        acc[i] += __shfl_xor(acc[i], 32);
    }
    if (q == 0) {
        int dg = end - beg;
        float inv = 1.0f / (float)(dg < 1 ? 1 : dg);
        ushort8 o;
        #pragma unroll
        for (int i = 0; i < 8; i++) o[i] = f2bf(acc[i] * inv);
        *(ushort8*)&out[(size_t)wid * D + colOff + cl * 8] = o;
    }
}

// ---------------- mean aggregation, 64-col quarter (A/B experiment) ----------------
// Per edge: 128B = exactly one TCC line. Working set 12.8MB/pass (~3x L2)
// vs half's 25.6MB -> fewer capacity misses on the 3.78 TB/s miss path.

__global__ __launch_bounds__(256)
void k_agg_q(const u16* __restrict__ h, const int* __restrict__ offs,
             const int* __restrict__ ends, const int* __restrict__ srcs,
             u16* __restrict__ out, int colOff, int N) {
    int wid = (blockIdx.x * blockDim.x + threadIdx.x) >> 6;
    int lane = threadIdx.x & 63;
    if (wid >= N) return;
    int beg = offs[wid], end = ends[wid];
    int q = lane >> 3;             // edge slot 0..7
    int cl = lane & 7;             // 16B chunk within the 128B quarter-row
    const u16* hb = h + colOff + cl * 8;
    float acc[8];
    #pragma unroll
    for (int i = 0; i < 8; i++) acc[i] = 0.f;
    int e = beg + q;
    for (; e + 24 < end; e += 32) {
        int j0 = srcs[e], j1 = srcs[e + 8], j2 = srcs[e + 16], j3 = srcs[e + 24];
        ushort8 v0 = *(const ushort8*)&hb[(size_t)j0 * D];
        ushort8 v1 = *(const ushort8*)&hb[(size_t)j1 * D];
        ushort8 v2 = *(const ushort8*)&hb[(size_t)j2 * D];
        ushort8 v3 = *(const ushort8*)&hb[(size_t)j3 * D];
        #pragma unroll
        for (int i = 0; i < 8; i++)
            acc[i] += (bf2f(v0[i]) + bf2f(v1[i])) + (bf2f(v2[i]) + bf2f(v3[i]));
    }
    for (; e < end; e += 8) {
        int j = srcs[e];
        ushort8 v = *(const ushort8*)&hb[(size_t)j * D];
        #pragma unroll
        for (int i = 0; i < 8; i++) acc[i] += bf2f(v[i]);
    }
    #pragma unroll
    for (int i = 0; i < 8; i++) {
        acc[i] += __shfl_xor(acc[i], 8);
        acc[i] += __shfl_xor(acc[i], 16);
        acc[i] += __shfl_xor(acc[i], 32);
    }
    if (q == 0) {
        int dg = end - beg;
        float inv = 1.0f / (float)(dg < 1 ? 1 : dg);
        ushort8 o;
        #pragma unroll
        for (int i = 0; i < 8; i++) o[i] = f2bf(acc[i] * inv);
        *(ushort8*)&out[(size_t)wid * D + colOff + cl * 8] = o;
    }
}

// ---------------- fused MFMA GEMM: triple-buffer BK=32, counted vmcnt ----------------
// out[M,256] = epi( sum_p Ap[M,256] @ Wp[256,256]^T + bias ), bf16 in, fp32 acc.
// BM=128, BN=256, BK=32; 512 thr = 8 waves (2Mx4N), per-wave 64x64.
// LDS 72KB (3 bufs: A 3x8K + B 3x16K) -> 2 blocks/CU (the max: 16 waves
// needs VGPR<=128, launch_bounds(512,4)). T3+T4: stage buf[t+2] each step,
// per-step wait vmcnt(3) (own 3 loads of buf[t] done; buf[t+1]'s 3 stay in
// flight ACROSS the barrier) -> 2-step (~700cy) load lookahead, never
// drained to 0 in the loop. Last step peels vmcnt(0).
// 64B LDS rows: swizzle stored_chunk = chunk ^ ((row>>1)&3) spreads the
// 16-lane r-group over all 8 bank-groups (2-way = free). Applied on the
// per-lane GLOBAL source (gload_lds dest stays linear, rule 21) and on the
// ds_read address (same involution).
// K accumulation order identical to the original BK=32 kernel.

__global__ __launch_bounds__(512, 4)
void k_fgemm(const u16* __restrict__ A0, const u16* __restrict__ W0,
             const u16* __restrict__ A1, const u16* __restrict__ W1,
             int npairs,
             const float* __restrict__ bias, const float* __restrict__ prelu_a,
             void* __restrict__ outp, int out_bf16, int M) {
    __shared__ u16 As[3][128 * 32];   // 8KB each
    __shared__ u16 Bs[3][256 * 32];   // 16KB each
    int t = threadIdx.x;
    int wave = t >> 6, lane = t & 63;
    int r = lane & 15, quad = lane >> 4;
    int wm = (wave & 1) * 64;
    int wn = (wave >> 1) * 64;
    int m0 = blockIdx.x * 128;

    f32x4 acc[4][4];
    #pragma unroll
    for (int i = 0; i < 4; i++)
        #pragma unroll
        for (int j = 0; j < 4; j++)
            acc[i][j] = (f32x4){0.f, 0.f, 0.f, 0.f};

    // staging: per wave-load, 64 lanes x 16B = 16 rows x 64B (4 chunks/row).
    int arow = wave * 16 + (lane >> 2);          // A row for this lane's 16B
    int scol = (((lane & 3) ^ ((lane >> 3) & 3)) << 3);  // pre-swizzled src col (u16)
    int nkt = npairs * 8;                        // K-steps of 32

    auto STAGE = [&](int buf, int kt) {
        const u16* Ag = (kt >= 8) ? A1 : A0;
        const u16* Wg = (kt >= 8) ? W1 : W0;
        int k0 = (kt & 7) * 32;
        load_lds16(Ag + (size_t)(m0 + arow) * D + k0 + scol,
                   &As[buf][wave * 512]);
        #pragma unroll
        for (int l = 0; l < 2; l++)
            load_lds16(Wg + (size_t)(l * 128 + arow) * D + k0 + scol,
                       &Bs[buf][l * 4096 + wave * 512]);
    };

    STAGE(0, 0);
    if (nkt > 1) STAGE(1, 1);

    int pch = quad ^ ((r >> 1) & 3);   // swizzled chunk for fragment reads
    int b0 = 0, b2 = 2;                // buf of step kt, buf to stage (kt+2)
    for (int kt = 0; kt < nkt; ++kt) {
        if (kt + 1 < nkt) asm volatile("s_waitcnt vmcnt(3)" ::: "memory");
        else              asm volatile("s_waitcnt vmcnt(0)" ::: "memory");
        __builtin_amdgcn_s_barrier();
        asm volatile("" ::: "memory");

        if (kt + 2 < nkt) STAGE(b2, kt + 2);

        short8 a[4], b[4];
        #pragma unroll
        for (int mt = 0; mt < 4; mt++)
            a[mt] = *(const short8*)&As[b0][(wm + mt * 16 + r) * 32 + pch * 8];
        #pragma unroll
        for (int nt = 0; nt < 4; nt++)
            b[nt] = *(const short8*)&Bs[b0][(wn + nt * 16 + r) * 32 + pch * 8];

        __builtin_amdgcn_s_setprio(1);
        #pragma unroll
        for (int mt = 0; mt < 4; mt++)
            #pragma unroll
            for (int nt = 0; nt < 4; nt++)
                acc[mt][nt] = __builtin_amdgcn_mfma_f32_16x16x32_bf16(
                    a[mt], b[nt], acc[mt][nt], 0, 0, 0);
        __builtin_amdgcn_s_setprio(0);

        b0 = (b0 == 2) ? 0 : b0 + 1;
        b2 = (b2 == 2) ? 0 : b2 + 1;
    }

    float pa = prelu_a ? *prelu_a : 0.f;
    int dop = prelu_a != nullptr;
    #pragma unroll
    for (int nt = 0; nt < 4; nt++) {
        int col = wn + nt * 16 + r;
        float bv = bias ? bias[col] : 0.f;
        #pragma unroll
        for (int mt = 0; mt < 4; mt++) {
            #pragma unroll
            for (int i = 0; i < 4; i++) {
                int row = m0 + wm + mt * 16 + quad * 4 + i;
                if (row < M) {
                    float v = acc[mt][nt][i] + bv;
                    if (dop) v = (v >= 0.f) ? v : pa * v;
                    if (out_bf16)
                        ((u16*)outp)[(size_t)row * D + col] = f2bf(v);
                    else
                        ((float*)outp)[(size_t)row * D + col] = v;
                }
            }
        }
    }
}

// ---------------- launcher ----------------

extern "C" void kernel_launch(void* const* d_in, const int* in_sizes, int n_in,
                              void* d_out, int out_size, void* d_ws, size_t ws_size,
                              hipStream_t stream) {
    const int*   x    = (const int*)d_in[0];
    const int*   ei   = (const int*)d_in[1];
    const float* emb  = (const float*)d_in[3];
    const float* Wl[3] = {(const float*)d_in[4],  (const float*)d_in[8],  (const float*)d_in[12]};
    const float* bl[3] = {(const float*)d_in[5],  (const float*)d_in[9],  (const float*)d_in[13]};
    const float* Wr[3] = {(const float*)d_in[6],  (const float*)d_in[10], (const float*)d_in[14]};
    const float* pa[3] = {(const float*)d_in[7],  (const float*)d_in[11], (const float*)d_in[15]};
    const float* Wout = (const float*)d_in[16];
    const float* bout = (const float*)d_in[17];

    int N = in_sizes[0];
    int E = in_sizes[1] / 2;
    const int* src = ei;
    const int* dst = ei + E;
    int nfbin = (N + 511) >> 9;    // 196 for N=100000

    char* ws = (char*)d_ws;
    size_t off = 0;
    auto walloc = [&](size_t bytes) -> void* {
        void* p = ws + off;
        off += (bytes + 255) & ~(size_t)255;
        return p;
    };
    // tile staging over-reads up to ~49 KB past row M-1: keep activations mid-ws
    u16* hA   = (u16*)walloc((size_t)N * D * sizeof(u16));
    u16* hB   = (u16*)walloc((size_t)N * D * sizeof(u16));
    u16* mean = (u16*)walloc((size_t)N * D * sizeof(u16));
    u16* wbf  = (u16*)walloc((size_t)7 * 65536 * sizeof(u16));
    int* offs   = (int*)walloc((size_t)N * sizeof(int));
    int* ends   = (int*)walloc((size_t)N * sizeof(int));
    int* bincur = (int*)walloc(1024);
    unsigned* bins = (unsigned*)walloc((size_t)nfbin * FBINCAP * sizeof(unsigned));
    int* srcs   = (int*)walloc((size_t)nfbin * FBINCAP * sizeof(int));

    u16* Wlb[3] = {wbf + 0 * 65536, wbf + 2 * 65536, wbf + 4 * 65536};
    u16* Wrb[3] = {wbf + 1 * 65536, wbf + 3 * 65536, wbf + 5 * 65536};
    u16* Woutb  = wbf + 6 * 65536;

    // --- weights -> bf16 ---
    k_cvtw<<<(7 * 65536 + 255) / 256, 256, 0, stream>>>(
        Wl[0], Wr[0], Wl[1], Wr[1], Wl[2], Wr[2], Wout, wbf);

    // --- CSR build: fine-bin + in-LDS sort ---
    k_initcur<<<1, 256, 0, stream>>>(bincur, nfbin);
    int bb = (E + BCHUNK - 1) / BCHUNK;
    k_binf<<<bb, 256, 0, stream>>>(src, dst, bincur, bins, E, nfbin);
    k_csrf<<<nfbin, 256, 0, stream>>>(bins, bincur, offs, ends, srcs, N);

    // --- h0 = bf16(emb[x]) ---
    k_gather_bf<<<(N * 64 + 255) / 256, 256, 0, stream>>>(x, emb, hA, N);

    int mb   = (N + 127) / 128;
    int aggb = (N * 64 + 255) / 256;   // one wave per dst node

    // layer 1: hA -> hB   (A/B experiment: quarter-split aggregation)
    k_agg_q<<<aggb, 256, 0, stream>>>(hA, offs, ends, srcs, mean, 0, N);
    k_agg_q<<<aggb, 256, 0, stream>>>(hA, offs, ends, srcs, mean, 64, N);
    k_agg_q<<<aggb, 256, 0, stream>>>(hA, offs, ends, srcs, mean, 128, N);
    k_agg_q<<<aggb, 256, 0, stream>>>(hA, offs, ends, srcs, mean, 192, N);
    k_fgemm<<<mb, 512, 0, stream>>>(mean, Wlb[0], hA, Wrb[0], 2, bl[0], pa[0], hB, 1, N);
    // layer 2: hB -> hA   (proven half-split)
    k_agg_h<<<aggb, 256, 0, stream>>>(hB, offs, ends, srcs, mean, 0, N);
    k_agg_h<<<aggb, 256, 0, stream>>>(hB, offs, ends, srcs, mean, 128, N);
    k_fgemm<<<mb, 512, 0, stream>>>(mean, Wlb[1], hB, Wrb[1], 2, bl[1], pa[1], hA, 1, N);
    // layer 3: hA -> hB
    k_agg_h<<<aggb, 256, 0, stream>>>(hA, offs, ends, srcs, mean, 0, N);
    k_agg_h<<<aggb, 256, 0, stream>>>(hA, offs, ends, srcs, mean, 128, N);
    k_fgemm<<<mb, 512, 0, stream>>>(mean, Wlb[2], hA, Wrb[2], 2, bl[2], pa[2], hB, 1, N);
    // output projection -> fp32 d_out
    k_fgemm<<<mb, 512, 0, stream>>>(hB, Woutb, hB, Woutb, 1, bout, nullptr, d_out, 0, N);
}